// Round 7
// baseline (2483.899 us; speedup 1.0000x reference)
//
#include <hip/hip_runtime.h>
#include <hip/hip_bf16.h>

#define GB 2  // batch elems per convB/conv2 block

__device__ __forceinline__ float elu1(float v) { return v > 0.f ? v : expm1f(v); }

// ---------------- cnorm: ||cb_k||^2 per code ----------------
__global__ void cnorm_kernel(const float* __restrict__ cb, float* __restrict__ cnorm) {
    int g = blockIdx.x * blockDim.x + threadIdx.x;  // 0..8191  (q*1024+k)
    if (g >= 8 * 1024) return;
    const float* p = cb + (size_t)g * 256;
    float s = 0.f;
    for (int d = 0; d < 256; d += 4) {
        float4 v = *reinterpret_cast<const float4*>(p + d);
        s += v.x * v.x + v.y * v.y + v.z * v.z + v.w * v.w;
    }
    cnorm[g] = s;
}

// ---------------- weight transpose to lane-major layouts ----------------
__global__ void wtrans_kernel(const float* __restrict__ W1, const float* __restrict__ W2,
                              const float* __restrict__ W3, float* __restrict__ W1T,
                              float* __restrict__ W2T, float* __restrict__ W3T) {
    int g = blockIdx.x * blockDim.x + threadIdx.x;
    if (g < 8192) {  // W1
        int ci = g >> 7, c = g & 127;
        const float* src = W1 + c * 512 + ci * 8;
        float4 a = *reinterpret_cast<const float4*>(src);
        float4 b = *reinterpret_cast<const float4*>(src + 4);
        *reinterpret_cast<float4*>(W1T + g * 8) = a;
        *reinterpret_cast<float4*>(W1T + g * 8 + 4) = b;
    }
    int g2 = g - 8192;
    if (g2 >= 0 && g2 < 32768) {  // W2
        int ci = g2 >> 8, c = g2 & 255;
        const float* src = W2 + c * 1280 + ci * 10;
        float* dst = W2T + g2 * 10;
#pragma unroll
        for (int j = 0; j < 5; ++j)
            *reinterpret_cast<float2*>(dst + 2 * j) =
                *reinterpret_cast<const float2*>(src + 2 * j);
    }
    int g3 = g - 40960;
    if (g3 >= 0 && g3 < 65536) {  // W3 (only taps 6..11 are ever used)
        int ci = g3 >> 8, c = g3 & 255;
        const float* src = W3 + c * 3072 + ci * 12 + 6;
        float* dst = W3T + g3 * 6;
#pragma unroll
        for (int j = 0; j < 3; ++j)
            *reinterpret_cast<float2*>(dst + 2 * j) =
                *reinterpret_cast<const float2*>(src + 2 * j);
    }
}

// ================= convA: conv0 + conv1 (round-5 proven, straight loop) ======
__global__ __launch_bounds__(256, 2)
void convA_kernel(const float* __restrict__ audio,
                  const float* __restrict__ W0, const float* __restrict__ b0,
                  const float* __restrict__ W1T, const float* __restrict__ b1,
                  float* __restrict__ y1g) {
    __shared__ __align__(16) float xs[244];
    __shared__ __align__(16) float y0s[64 * 124];  // 4 left pad cols

    const int tid = threadIdx.x;
    const int b = blockIdx.x;

    if (tid < 64) {
        y0s[tid * 124 + 0] = 0.f; y0s[tid * 124 + 1] = 0.f;
        y0s[tid * 124 + 2] = 0.f; y0s[tid * 124 + 3] = 0.f;
    }
    if (tid < 242) xs[tid] = (tid < 2) ? 0.f : audio[b * 240 + tid - 2];
    __syncthreads();
    {
        const int ci = tid >> 2, tg = tid & 3;
        float4 w = *reinterpret_cast<const float4*>(W0 + ci * 4);
        float bias = b0[ci];
        for (int t = tg; t < 120; t += 4) {
            float v = bias + w.x * xs[2 * t] + w.y * xs[2 * t + 1]
                           + w.z * xs[2 * t + 2] + w.w * xs[2 * t + 3];
            y0s[ci * 124 + 4 + t] = elu1(v);
        }
    }
    __syncthreads();
    {
        const int c = tid >> 1, half = tid & 1, t0 = 15 * half;
        float acc[15];
        float bias = b1[c];
#pragma unroll
        for (int u = 0; u < 15; ++u) acc[u] = bias;
        const float* wbase = W1T + c * 8;  // + ci*1024
        for (int ci = 0; ci < 64; ++ci) {
            float4 wA = *reinterpret_cast<const float4*>(wbase + ci * 1024);
            float4 wB = *reinterpret_cast<const float4*>(wbase + ci * 1024 + 4);
            const float* yb = y0s + ci * 124 + 4 * t0;
#pragma unroll
            for (int u = 0; u < 15; ++u) {
                float4 a = *reinterpret_cast<const float4*>(yb + 4 * u);
                float4 d = *reinterpret_cast<const float4*>(yb + 4 * u + 4);
                acc[u] += wA.x * a.x + wA.y * a.y + wA.z * a.z + wA.w * a.w
                        + wB.x * d.x + wB.y * d.y + wB.z * d.z + wB.w * d.w;
            }
        }
        float* yo = y1g + ((size_t)b * 128 + c) * 32 + t0;
#pragma unroll
        for (int u = 0; u < 15; ++u) yo[u] = elu1(acc[u]);
    }
}

// ================= convB fused fallback (round-5 proven) =====================
__global__ __launch_bounds__(256, 2)
void convB_kernel(const float* __restrict__ state_in,
                  const float* __restrict__ b2, const float* __restrict__ b3,
                  const float* __restrict__ W2T, const float* __restrict__ W3T,
                  const float* __restrict__ y1g,
                  float* __restrict__ out, float* __restrict__ r_ws) {
    __shared__ __align__(16) float y1s[GB * 128 * 32];
    __shared__ __align__(16) float y2s[GB * 256 * 6];

    const int tid = threadIdx.x;
    const int bbase = blockIdx.x * GB;

    {
        const int col = tid & 31, grp = tid >> 5;
#pragma unroll
        for (int bi = 0; bi < GB; ++bi) {
            const float* src = y1g + ((size_t)(bbase + bi) * 128 + grp * 16) * 32 + col;
            float* dst = y1s + (bi * 128 + grp * 16) * 32 + col;
#pragma unroll
            for (int i = 0; i < 16; ++i) dst[i * 32] = src[i * 32];
        }
    }
    __syncthreads();
    {
        const int c = tid;
        float acc[GB][6];
        float bias = b2[c];
#pragma unroll
        for (int bi = 0; bi < GB; ++bi)
#pragma unroll
            for (int t = 0; t < 6; ++t) acc[bi][t] = bias;
        const float* wbase = W2T + c * 10;
        for (int ci = 0; ci < 128; ++ci) {
            float w[10];
#pragma unroll
            for (int jj = 0; jj < 5; ++jj) {
                float2 wv = *reinterpret_cast<const float2*>(wbase + ci * 2560 + jj * 2);
                w[jj * 2] = wv.x; w[jj * 2 + 1] = wv.y;
            }
#pragma unroll
            for (int bi = 0; bi < GB; ++bi) {
                const float* yr = y1s + (bi * 128 + ci) * 32;
                float row[32];
#pragma unroll
                for (int k4 = 0; k4 < 8; ++k4) {
                    float4 v = *reinterpret_cast<const float4*>(yr + k4 * 4);
                    row[k4 * 4] = v.x; row[k4 * 4 + 1] = v.y;
                    row[k4 * 4 + 2] = v.z; row[k4 * 4 + 3] = v.w;
                }
                acc[bi][0] += w[5] * row[0] + w[6] * row[1] + w[7] * row[2]
                            + w[8] * row[3] + w[9] * row[4];
#pragma unroll
                for (int t = 1; t < 6; ++t) {
                    const int q0 = 5 * t - 5;
                    float s = 0.f;
#pragma unroll
                    for (int j = 0; j < 10; ++j) s += w[j] * row[q0 + j];
                    acc[bi][t] += s;
                }
            }
        }
#pragma unroll
        for (int bi = 0; bi < GB; ++bi)
#pragma unroll
            for (int t = 0; t < 6; ++t)
                y2s[(bi * 256 + c) * 6 + t] = elu1(acc[bi][t]);
    }
    __syncthreads();
    {
        const int c = tid;
        float acc[GB];
        float bias = b3[c];
#pragma unroll
        for (int bi = 0; bi < GB; ++bi) acc[bi] = bias;
        const float* wbase = W3T + c * 6;
        for (int ci = 0; ci < 256; ++ci) {
            float2 w01 = *reinterpret_cast<const float2*>(wbase + ci * 1536);
            float2 w23 = *reinterpret_cast<const float2*>(wbase + ci * 1536 + 2);
            float2 w45 = *reinterpret_cast<const float2*>(wbase + ci * 1536 + 4);
#pragma unroll
            for (int bi = 0; bi < GB; ++bi) {
                const float* yr = y2s + (bi * 256 + ci) * 6;
                float2 a = *reinterpret_cast<const float2*>(yr);
                float2 d = *reinterpret_cast<const float2*>(yr + 2);
                float2 e = *reinterpret_cast<const float2*>(yr + 4);
                acc[bi] += w01.x * a.x + w01.y * a.y + w23.x * d.x + w23.y * d.y
                         + w45.x * e.x + w45.y * e.y;
            }
        }
#pragma unroll
        for (int bi = 0; bi < GB; ++bi) {
            const int b = bbase + bi;
            float y3 = acc[bi];
            r_ws[b * 256 + c] = y3;
            float4 si = *reinterpret_cast<const float4*>(state_in + b * 1024 + c * 4);
            float4 o; o.x = si.y; o.y = si.z; o.z = si.w; o.w = y3;
            *reinterpret_cast<float4*>(out + 65536 + b * 1024 + c * 4) = o;
        }
    }
}

// ================= SPLIT: conv2 only (LDS 32KB -> 4 blocks/CU) ===============
__global__ __launch_bounds__(256, 2)
void conv2_kernel(const float* __restrict__ b2, const float* __restrict__ W2T,
                  const float* __restrict__ y1g, float* __restrict__ y2g) {
    __shared__ __align__(16) float y1s[GB * 128 * 32];

    const int tid = threadIdx.x;
    const int bbase = blockIdx.x * GB;

    {
        const int col = tid & 31, grp = tid >> 5;
#pragma unroll
        for (int bi = 0; bi < GB; ++bi) {
            const float* src = y1g + ((size_t)(bbase + bi) * 128 + grp * 16) * 32 + col;
            float* dst = y1s + (bi * 128 + grp * 16) * 32 + col;
#pragma unroll
            for (int i = 0; i < 16; ++i) dst[i * 32] = src[i * 32];
        }
    }
    __syncthreads();
    {
        const int c = tid;
        float acc[GB][6];
        float bias = b2[c];
#pragma unroll
        for (int bi = 0; bi < GB; ++bi)
#pragma unroll
            for (int t = 0; t < 6; ++t) acc[bi][t] = bias;
        const float* wbase = W2T + c * 10;
        for (int ci = 0; ci < 128; ++ci) {
            float w[10];
#pragma unroll
            for (int jj = 0; jj < 5; ++jj) {
                float2 wv = *reinterpret_cast<const float2*>(wbase + ci * 2560 + jj * 2);
                w[jj * 2] = wv.x; w[jj * 2 + 1] = wv.y;
            }
#pragma unroll
            for (int bi = 0; bi < GB; ++bi) {
                const float* yr = y1s + (bi * 128 + ci) * 32;
                float row[32];
#pragma unroll
                for (int k4 = 0; k4 < 8; ++k4) {
                    float4 v = *reinterpret_cast<const float4*>(yr + k4 * 4);
                    row[k4 * 4] = v.x; row[k4 * 4 + 1] = v.y;
                    row[k4 * 4 + 2] = v.z; row[k4 * 4 + 3] = v.w;
                }
                acc[bi][0] += w[5] * row[0] + w[6] * row[1] + w[7] * row[2]
                            + w[8] * row[3] + w[9] * row[4];
#pragma unroll
                for (int t = 1; t < 6; ++t) {
                    const int q0 = 5 * t - 5;
                    float s = 0.f;
#pragma unroll
                    for (int j = 0; j < 10; ++j) s += w[j] * row[q0 + j];
                    acc[bi][t] += s;
                }
            }
        }
#pragma unroll
        for (int bi = 0; bi < GB; ++bi) {
            float* dst = y2g + ((size_t)(bbase + bi) * 256 + c) * 6;
#pragma unroll
            for (int jj = 0; jj < 3; ++jj) {
                float2 o; o.x = elu1(acc[bi][jj * 2]); o.y = elu1(acc[bi][jj * 2 + 1]);
                *reinterpret_cast<float2*>(dst + jj * 2) = o;
            }
        }
    }
}

// ================= SPLIT: conv3 + state (tiny, high occupancy) ===============
__global__ __launch_bounds__(256)
void conv3_kernel(const float* __restrict__ state_in, const float* __restrict__ b3,
                  const float* __restrict__ W3T, const float* __restrict__ y2g,
                  float* __restrict__ out, float* __restrict__ r_ws) {
    __shared__ __align__(16) float y2s[256 * 8];  // padded stride 8

    const int tid = threadIdx.x;
    const int b = blockIdx.x;

    {
        const float* src = y2g + ((size_t)b * 256 + tid) * 6;
        float* dst = y2s + tid * 8;
#pragma unroll
        for (int jj = 0; jj < 3; ++jj)
            *reinterpret_cast<float2*>(dst + jj * 2) =
                *reinterpret_cast<const float2*>(src + jj * 2);
    }
    __syncthreads();
    {
        const int c = tid;
        float acc = b3[c];
        const float* wbase3 = W3T + c * 6;
        for (int ci = 0; ci < 256; ++ci) {
            float2 w01 = *reinterpret_cast<const float2*>(wbase3 + ci * 1536);
            float2 w23 = *reinterpret_cast<const float2*>(wbase3 + ci * 1536 + 2);
            float2 w45 = *reinterpret_cast<const float2*>(wbase3 + ci * 1536 + 4);
            const float* yr = y2s + ci * 8;
            float2 a = *reinterpret_cast<const float2*>(yr);
            float2 d = *reinterpret_cast<const float2*>(yr + 2);
            float2 e = *reinterpret_cast<const float2*>(yr + 4);
            acc += w01.x * a.x + w01.y * a.y + w23.x * d.x + w23.y * d.y
                 + w45.x * e.x + w45.y * e.y;
        }
        r_ws[b * 256 + c] = acc;
        float4 si = *reinterpret_cast<const float4*>(state_in + b * 1024 + c * 4);
        float4 o; o.x = si.y; o.y = si.z; o.z = si.w; o.w = acc;
        *reinterpret_cast<float4*>(out + 65536 + b * 1024 + c * 4) = o;
    }
}

// ---------------- RVQ v3: occupancy-oriented register GEMM ----------------
// 512 thr = 8 waves, 16 b per block, grid 512 -> 2 blocks/CU (16 waves/CU).
// Stage = 8 d x 1024 k in cbs[8][1024] (k-contiguous: b128 reads conflict-free,
// stores 2-way=free, no swizzle). Wave = (bg of 8 b) x (kg quarter of 256 k);
// thread tile 8b x 4k. Global prefetch one stage ahead.
__device__ __forceinline__ unsigned long long distkey(float d, int k) {
    unsigned u = __float_as_uint(d);
    u = (u & 0x80000000u) ? ~u : (u | 0x80000000u);  // monotonic float->uint
    return ((unsigned long long)u << 32) | (unsigned)k;  // low idx wins ties (np argmin)
}

__global__ __launch_bounds__(512)
void rvq_kernel(const float* __restrict__ cb, const float* __restrict__ cnorm,
                const float* __restrict__ r_ws, float* __restrict__ out) {
    __shared__ __align__(16) float rs[16 * 256];   // 16 KB residuals
    __shared__ __align__(16) float cbs[8 * 1024];  // 32 KB, [d_local][k]
    __shared__ unsigned long long part_sh[4][16];
    __shared__ int idx_sh[16];

    const int tid = threadIdx.x;
    const int lane = tid & 63;
    const int wid = tid >> 6;   // 0..7
    const int bg = wid >> 2;    // 0..1: b block of 8
    const int kg = wid & 3;     // 0..3: k quarter of 256
    const int b0 = blockIdx.x * 16;
    const int kbase = kg * 256 + 4 * lane;

    // load residuals (coalesced)
    for (int it = 0; it < 2; ++it) {
        int o = (it * 512 + tid) * 4;
        *reinterpret_cast<float4*>(rs + o) =
            *reinterpret_cast<const float4*>(r_ws + b0 * 256 + o);
    }

    // staging roles: 2 threads per k-row cover the 8-d slice
    const int sk = tid >> 1;   // 0..255
    const int sdq = tid & 1;   // which d-quad of the slice

    // prefetch stage 0 (q=0, ds=0)
    float v[4][4];
    {
        const float* src = cb + (size_t)sk * 256 + sdq * 4;
#pragma unroll
        for (int p = 0; p < 4; ++p) {
            float4 t = *reinterpret_cast<const float4*>(src + (size_t)p * 256 * 256);
            v[p][0] = t.x; v[p][1] = t.y; v[p][2] = t.z; v[p][3] = t.w;
        }
    }

    for (int q = 0; q < 8; ++q) {
        float acc[8][4];
#pragma unroll
        for (int i = 0; i < 8; ++i)
#pragma unroll
            for (int j = 0; j < 4; ++j) acc[i][j] = 0.f;

        for (int ds = 0; ds < 32; ++ds) {
            __syncthreads();  // all waves done reading cbs (previous stage)
#pragma unroll
            for (int m = 0; m < 4; ++m) {
                const int d = sdq * 4 + m;
#pragma unroll
                for (int p = 0; p < 4; ++p)
                    cbs[d * 1024 + p * 256 + sk] = v[p][m];
            }
            {   // prefetch next stage (clamped; harmless dup at the very end)
                int Sn = q * 32 + ds + 1; if (Sn > 255) Sn = 255;
                const int qn = Sn >> 5, dsn = Sn & 31;
                const float* src = cb + ((size_t)(qn * 1024 + sk)) * 256 + dsn * 8 + sdq * 4;
#pragma unroll
                for (int p = 0; p < 4; ++p) {
                    float4 t = *reinterpret_cast<const float4*>(src + (size_t)p * 256 * 256);
                    v[p][0] = t.x; v[p][1] = t.y; v[p][2] = t.z; v[p][3] = t.w;
                }
            }
            __syncthreads();  // cbs stores visible
            // compute the 8-d slice
#pragma unroll
            for (int dp = 0; dp < 2; ++dp) {
                float rr[8][4];
#pragma unroll
                for (int i = 0; i < 8; ++i) {
                    float4 t = *reinterpret_cast<const float4*>(
                        rs + (bg * 8 + i) * 256 + ds * 8 + dp * 4);
                    rr[i][0] = t.x; rr[i][1] = t.y; rr[i][2] = t.z; rr[i][3] = t.w;
                }
#pragma unroll
                for (int dd = 0; dd < 4; ++dd) {
                    const int d = dp * 4 + dd;
                    float4 cv = *reinterpret_cast<const float4*>(cbs + d * 1024 + kbase);
#pragma unroll
                    for (int i = 0; i < 8; ++i) {
                        const float r = rr[i][dd];
                        acc[i][0] += r * cv.x; acc[i][1] += r * cv.y;
                        acc[i][2] += r * cv.z; acc[i][3] += r * cv.w;
                    }
                }
            }
        }
        // ---- argmin over this wave's 4 k's x 8 b's ----
        unsigned long long wkey[8];
#pragma unroll
        for (int i = 0; i < 8; ++i) wkey[i] = 0xFFFFFFFFFFFFFFFFull;
        {
            float4 cn = *reinterpret_cast<const float4*>(cnorm + q * 1024 + kbase);
            float cne[4] = {cn.x, cn.y, cn.z, cn.w};
#pragma unroll
            for (int e = 0; e < 4; ++e)
#pragma unroll
                for (int i = 0; i < 8; ++i) {
                    unsigned long long kk2 =
                        distkey(cne[e] - 2.f * acc[i][e], kbase + e);
                    if (kk2 < wkey[i]) wkey[i] = kk2;
                }
        }
#pragma unroll
        for (int i = 0; i < 8; ++i) {
            unsigned long long k = wkey[i];
            for (int off = 32; off >= 1; off >>= 1) {
                unsigned long long o = __shfl_xor(k, off, 64);
                if (o < k) k = o;
            }
            if (lane == 0) part_sh[kg][bg * 8 + i] = k;
        }
        __syncthreads();
        if (tid < 16) {
            unsigned long long ka = part_sh[0][tid];
            if (part_sh[1][tid] < ka) ka = part_sh[1][tid];
            if (part_sh[2][tid] < ka) ka = part_sh[2][tid];
            if (part_sh[3][tid] < ka) ka = part_sh[3][tid];
            const int idx = (int)(ka & 0xFFFFFFFFu);
            idx_sh[tid] = idx;
            out[(b0 + tid) * 8 + q] = (float)idx;
        }
        __syncthreads();
        // residual update (4096 elems / 512 thr = 8)
        for (int it = 0; it < 8; ++it) {
            int flat = it * 512 + tid;
            int bL = flat >> 8, d = flat & 255;
            rs[bL * 256 + d] -= cb[((size_t)(q * 1024 + idx_sh[bL])) * 256 + d];
        }
        // next q's stage-0 barriers make these rs writes visible
    }
}

extern "C" void kernel_launch(void* const* d_in, const int* in_sizes, int n_in,
                              void* d_out, int out_size, void* d_ws, size_t ws_size,
                              hipStream_t stream) {
    const float* audio = (const float*)d_in[0];
    const float* state = (const float*)d_in[1];
    const float* W0 = (const float*)d_in[2];
    const float* b0 = (const float*)d_in[3];
    const float* W1 = (const float*)d_in[4];
    const float* b1 = (const float*)d_in[5];
    const float* W2 = (const float*)d_in[6];
    const float* b2 = (const float*)d_in[7];
    const float* W3 = (const float*)d_in[8];
    const float* b3 = (const float*)d_in[9];
    const float* cbk = (const float*)d_in[10];
    float* out = (float*)d_out;

    float* cnorm_ws = (float*)d_ws;            // 8192
    float* r_ws = cnorm_ws + 8192;             // 2097152
    float* W1T = r_ws + 2097152;               // 65536
    float* W2T = W1T + 65536;                  // 327680
    float* W3T = W2T + 327680;                 // 393216
    float* y1g = W3T + 393216;                 // 33554432 (134MB; ws>=146MB confirmed r3)
    float* y2g = y1g + 33554432;               // 12582912 (50MB; split path only)

    const unsigned long long need_split = 49029120ull * 4ull;  // ~196 MB
    const bool split = ws_size >= need_split;

    cnorm_kernel<<<32, 256, 0, stream>>>(cbk, cnorm_ws);
    wtrans_kernel<<<416, 256, 0, stream>>>(W1, W2, W3, W1T, W2T, W3T);
    convA_kernel<<<8192, 256, 0, stream>>>(audio, W0, b0, W1T, b1, y1g);
    if (split) {
        conv2_kernel<<<8192 / GB, 256, 0, stream>>>(b2, W2T, y1g, y2g);
        conv3_kernel<<<8192, 256, 0, stream>>>(state, b3, W3T, y2g, out, r_ws);
    } else {
        convB_kernel<<<8192 / GB, 256, 0, stream>>>(state, b2, b3, W2T, W3T, y1g,
                                                    out, r_ws);
    }
    rvq_kernel<<<512, 512, 0, stream>>>(cbk, cnorm_ws, r_ws, out);
}

// Round 9
// 2354.144 us; speedup vs baseline: 1.0551x; 1.0551x over previous
//
#include <hip/hip_runtime.h>
#include <hip/hip_bf16.h>

#define GB 2  // batch elems per convB block

__device__ __forceinline__ float elu1(float v) { return v > 0.f ? v : expm1f(v); }

// ---------------- cnorm: ||cb_k||^2 per code ----------------
__global__ void cnorm_kernel(const float* __restrict__ cb, float* __restrict__ cnorm) {
    int g = blockIdx.x * blockDim.x + threadIdx.x;  // 0..8191  (q*1024+k)
    if (g >= 8 * 1024) return;
    const float* p = cb + (size_t)g * 256;
    float s = 0.f;
    for (int d = 0; d < 256; d += 4) {
        float4 v = *reinterpret_cast<const float4*>(p + d);
        s += v.x * v.x + v.y * v.y + v.z * v.z + v.w * v.w;
    }
    cnorm[g] = s;
}

// ---------------- cbtrans: codebook -> staged layout for global_load_lds -----
// cbT[(s*8 + dl)*1024 + k] = cb[((s>>5)*1024 + k)*256 + (s&31)*8 + dl]
__global__ void cbtrans_kernel(const float* __restrict__ cb, float* __restrict__ cbT) {
    int t = blockIdx.x * blockDim.x + threadIdx.x;  // 0..524287 (float4 units)
    int o = t * 4;
    const int s = o >> 13;          // stage 0..255
    const int r = o & 8191;
    const int dl = r >> 10;
    const int k = r & 1023;         // k, k+1, k+2, k+3
    const int q = s >> 5;
    const int d = (s & 31) * 8 + dl;
    const float* src = cb + ((size_t)(q * 1024 + k)) * 256 + d;
    float4 v;
    v.x = src[0 * 256]; v.y = src[1 * 256]; v.z = src[2 * 256]; v.w = src[3 * 256];
    *reinterpret_cast<float4*>(cbT + o) = v;
}

// ---------------- weight transpose to lane-major layouts ----------------
__global__ void wtrans_kernel(const float* __restrict__ W1, const float* __restrict__ W2,
                              const float* __restrict__ W3, float* __restrict__ W1T,
                              float* __restrict__ W2T, float* __restrict__ W3T) {
    int g = blockIdx.x * blockDim.x + threadIdx.x;
    if (g < 8192) {  // W1
        int ci = g >> 7, c = g & 127;
        const float* src = W1 + c * 512 + ci * 8;
        float4 a = *reinterpret_cast<const float4*>(src);
        float4 b = *reinterpret_cast<const float4*>(src + 4);
        *reinterpret_cast<float4*>(W1T + g * 8) = a;
        *reinterpret_cast<float4*>(W1T + g * 8 + 4) = b;
    }
    int g2 = g - 8192;
    if (g2 >= 0 && g2 < 32768) {  // W2
        int ci = g2 >> 8, c = g2 & 255;
        const float* src = W2 + c * 1280 + ci * 10;
        float* dst = W2T + g2 * 10;
#pragma unroll
        for (int j = 0; j < 5; ++j)
            *reinterpret_cast<float2*>(dst + 2 * j) =
                *reinterpret_cast<const float2*>(src + 2 * j);
    }
    int g3 = g - 40960;
    if (g3 >= 0 && g3 < 65536) {  // W3 (only taps 6..11 are ever used)
        int ci = g3 >> 8, c = g3 & 255;
        const float* src = W3 + c * 3072 + ci * 12 + 6;
        float* dst = W3T + g3 * 6;
#pragma unroll
        for (int j = 0; j < 3; ++j)
            *reinterpret_cast<float2*>(dst + 2 * j) =
                *reinterpret_cast<const float2*>(src + 2 * j);
    }
}

// ================= convA: conv0 + conv1 (r5 proven) ==========================
__global__ __launch_bounds__(256, 2)
void convA_kernel(const float* __restrict__ audio,
                  const float* __restrict__ W0, const float* __restrict__ b0,
                  const float* __restrict__ W1T, const float* __restrict__ b1,
                  float* __restrict__ y1g) {
    __shared__ __align__(16) float xs[244];
    __shared__ __align__(16) float y0s[64 * 124];  // 4 left pad cols

    const int tid = threadIdx.x;
    const int b = blockIdx.x;

    if (tid < 64) {
        y0s[tid * 124 + 0] = 0.f; y0s[tid * 124 + 1] = 0.f;
        y0s[tid * 124 + 2] = 0.f; y0s[tid * 124 + 3] = 0.f;
    }
    if (tid < 242) xs[tid] = (tid < 2) ? 0.f : audio[b * 240 + tid - 2];
    __syncthreads();
    {
        const int ci = tid >> 2, tg = tid & 3;
        float4 w = *reinterpret_cast<const float4*>(W0 + ci * 4);
        float bias = b0[ci];
        for (int t = tg; t < 120; t += 4) {
            float v = bias + w.x * xs[2 * t] + w.y * xs[2 * t + 1]
                           + w.z * xs[2 * t + 2] + w.w * xs[2 * t + 3];
            y0s[ci * 124 + 4 + t] = elu1(v);
        }
    }
    __syncthreads();
    {
        const int c = tid >> 1, half = tid & 1, t0 = 15 * half;
        float acc[15];
        float bias = b1[c];
#pragma unroll
        for (int u = 0; u < 15; ++u) acc[u] = bias;
        const float* wbase = W1T + c * 8;  // + ci*1024
        for (int ci = 0; ci < 64; ++ci) {
            float4 wA = *reinterpret_cast<const float4*>(wbase + ci * 1024);
            float4 wB = *reinterpret_cast<const float4*>(wbase + ci * 1024 + 4);
            const float* yb = y0s + ci * 124 + 4 * t0;
#pragma unroll
            for (int u = 0; u < 15; ++u) {
                float4 a = *reinterpret_cast<const float4*>(yb + 4 * u);
                float4 d = *reinterpret_cast<const float4*>(yb + 4 * u + 4);
                acc[u] += wA.x * a.x + wA.y * a.y + wA.z * a.z + wA.w * a.w
                        + wB.x * d.x + wB.y * d.y + wB.z * d.z + wB.w * d.w;
            }
        }
        float* yo = y1g + ((size_t)b * 128 + c) * 32 + t0;
#pragma unroll
        for (int u = 0; u < 15; ++u) yo[u] = elu1(acc[u]);
    }
}

// ================= convB fused (r5 proven) ===================================
__global__ __launch_bounds__(256, 2)
void convB_kernel(const float* __restrict__ state_in,
                  const float* __restrict__ b2, const float* __restrict__ b3,
                  const float* __restrict__ W2T, const float* __restrict__ W3T,
                  const float* __restrict__ y1g,
                  float* __restrict__ out, float* __restrict__ r_ws) {
    __shared__ __align__(16) float y1s[GB * 128 * 32];
    __shared__ __align__(16) float y2s[GB * 256 * 6];

    const int tid = threadIdx.x;
    const int bbase = blockIdx.x * GB;

    {
        const int col = tid & 31, grp = tid >> 5;
#pragma unroll
        for (int bi = 0; bi < GB; ++bi) {
            const float* src = y1g + ((size_t)(bbase + bi) * 128 + grp * 16) * 32 + col;
            float* dst = y1s + (bi * 128 + grp * 16) * 32 + col;
#pragma unroll
            for (int i = 0; i < 16; ++i) dst[i * 32] = src[i * 32];
        }
    }
    __syncthreads();
    {
        const int c = tid;
        float acc[GB][6];
        float bias = b2[c];
#pragma unroll
        for (int bi = 0; bi < GB; ++bi)
#pragma unroll
            for (int t = 0; t < 6; ++t) acc[bi][t] = bias;
        const float* wbase = W2T + c * 10;
        for (int ci = 0; ci < 128; ++ci) {
            float w[10];
#pragma unroll
            for (int jj = 0; jj < 5; ++jj) {
                float2 wv = *reinterpret_cast<const float2*>(wbase + ci * 2560 + jj * 2);
                w[jj * 2] = wv.x; w[jj * 2 + 1] = wv.y;
            }
#pragma unroll
            for (int bi = 0; bi < GB; ++bi) {
                const float* yr = y1s + (bi * 128 + ci) * 32;
                float row[32];
#pragma unroll
                for (int k4 = 0; k4 < 8; ++k4) {
                    float4 v = *reinterpret_cast<const float4*>(yr + k4 * 4);
                    row[k4 * 4] = v.x; row[k4 * 4 + 1] = v.y;
                    row[k4 * 4 + 2] = v.z; row[k4 * 4 + 3] = v.w;
                }
                acc[bi][0] += w[5] * row[0] + w[6] * row[1] + w[7] * row[2]
                            + w[8] * row[3] + w[9] * row[4];
#pragma unroll
                for (int t = 1; t < 6; ++t) {
                    const int q0 = 5 * t - 5;
                    float s = 0.f;
#pragma unroll
                    for (int j = 0; j < 10; ++j) s += w[j] * row[q0 + j];
                    acc[bi][t] += s;
                }
            }
        }
#pragma unroll
        for (int bi = 0; bi < GB; ++bi)
#pragma unroll
            for (int t = 0; t < 6; ++t)
                y2s[(bi * 256 + c) * 6 + t] = elu1(acc[bi][t]);
    }
    __syncthreads();
    {
        const int c = tid;
        float acc[GB];
        float bias = b3[c];
#pragma unroll
        for (int bi = 0; bi < GB; ++bi) acc[bi] = bias;
        const float* wbase = W3T + c * 6;
        for (int ci = 0; ci < 256; ++ci) {
            float2 w01 = *reinterpret_cast<const float2*>(wbase + ci * 1536);
            float2 w23 = *reinterpret_cast<const float2*>(wbase + ci * 1536 + 2);
            float2 w45 = *reinterpret_cast<const float2*>(wbase + ci * 1536 + 4);
#pragma unroll
            for (int bi = 0; bi < GB; ++bi) {
                const float* yr = y2s + (bi * 256 + ci) * 6;
                float2 a = *reinterpret_cast<const float2*>(yr);
                float2 d = *reinterpret_cast<const float2*>(yr + 2);
                float2 e = *reinterpret_cast<const float2*>(yr + 4);
                acc[bi] += w01.x * a.x + w01.y * a.y + w23.x * d.x + w23.y * d.y
                         + w45.x * e.x + w45.y * e.y;
            }
        }
#pragma unroll
        for (int bi = 0; bi < GB; ++bi) {
            const int b = bbase + bi;
            float y3 = acc[bi];
            r_ws[b * 256 + c] = y3;
            float4 si = *reinterpret_cast<const float4*>(state_in + b * 1024 + c * 4);
            float4 o; o.x = si.y; o.y = si.z; o.z = si.w; o.w = y3;
            *reinterpret_cast<float4*>(out + 65536 + b * 1024 + c * 4) = o;
        }
    }
}

// ---------------- RVQ v5: dbuf + coalesced global_load_lds(16B) --------------
// 256 thr = 4 waves (2 bg x 2 kg), 16 b/block, grid 512 -> 2 blocks/CU.
// Stage s=(q,ds): cbs[s&1][8d][1024k] filled by 32 width-16 global_load_lds
// from the pre-transposed cbT (fully contiguous src & dest; 8 instrs/wave).
// One barrier per stage; prefetch issued post-barrier so its latency hides
// under the 512-FMA compute block and drains at the NEXT barrier.
__device__ __forceinline__ unsigned long long distkey(float d, int k) {
    unsigned u = __float_as_uint(d);
    u = (u & 0x80000000u) ? ~u : (u | 0x80000000u);  // monotonic float->uint
    return ((unsigned long long)u << 32) | (unsigned)k;  // low idx wins ties (np argmin)
}

#define RVQ_STAGE(S, BUF)                                                        \
    {                                                                            \
        _Pragma("unroll")                                                        \
        for (int j = 0; j < 8; ++j) {                                            \
            const int c_ = wid * 8 + j; /* 0..31: chunk of 256 floats */         \
            const float* g = cbT + (size_t)(S) * 8192 + c_ * 256 + lane * 4;     \
            __builtin_amdgcn_global_load_lds(                                    \
                (const __attribute__((address_space(1))) unsigned int*)g,        \
                (__attribute__((address_space(3))) unsigned int*)                \
                    (&cbs[BUF][0][0] + c_ * 256),                                \
                16, 0, 0);                                                       \
        }                                                                        \
    }

__global__ __launch_bounds__(256)
void rvq_kernel(const float* __restrict__ cb, const float* __restrict__ cbT,
                const float* __restrict__ cnorm, const float* __restrict__ r_ws,
                float* __restrict__ out,
                volatile unsigned long long* partg, volatile int* idxg) {
    __shared__ __align__(16) float rs[16 * 256];      // 16 KB residuals
    __shared__ __align__(16) float cbs[2][8][1024];   // 64 KB double-buffered

    const int tid = threadIdx.x;
    const int lane = tid & 63;
    const int wid = tid >> 6;   // 0..3
    const int bg = wid >> 1;    // 0..1: b block of 8
    const int kg = wid & 1;     // 0..1: k half of 512
    const int blk = blockIdx.x;
    const int b0 = blk * 16;
    const int kb = kg * 512 + 4 * lane;  // cv0 k-base (cv1 = +256)

    // load residuals: 4096 floats
    for (int it = 0; it < 4; ++it) {
        int o = (it * 256 + tid) * 4;
        *reinterpret_cast<float4*>(rs + o) =
            *reinterpret_cast<const float4*>(r_ws + b0 * 256 + o);
    }

    RVQ_STAGE(0, 0)

    for (int q = 0; q < 8; ++q) {
        float acc[8][8];
#pragma unroll
        for (int i = 0; i < 8; ++i)
#pragma unroll
            for (int j = 0; j < 8; ++j) acc[i][j] = 0.f;

        for (int ds = 0; ds < 32; ++ds) {
            const int s = q * 32 + ds;
            __syncthreads();  // stage-s data landed; prev readers done with buf^1
            {
                int Sn = s + 1; if (Sn > 255) Sn = 255;
                RVQ_STAGE(Sn, (s + 1) & 1)
            }
            const float* cbp = &cbs[s & 1][0][0];
#pragma unroll
            for (int dp = 0; dp < 2; ++dp) {
                float rr[8][4];
#pragma unroll
                for (int i = 0; i < 8; ++i) {
                    float4 t = *reinterpret_cast<const float4*>(
                        rs + (bg * 8 + i) * 256 + ds * 8 + dp * 4);
                    rr[i][0] = t.x; rr[i][1] = t.y; rr[i][2] = t.z; rr[i][3] = t.w;
                }
#pragma unroll
                for (int dd = 0; dd < 4; ++dd) {
                    const int dl = dp * 4 + dd;
                    float4 cv0 = *reinterpret_cast<const float4*>(cbp + dl * 1024 + kb);
                    float4 cv1 = *reinterpret_cast<const float4*>(
                        cbp + dl * 1024 + kb + 256);
#pragma unroll
                    for (int i = 0; i < 8; ++i) {
                        const float r = rr[i][dd];
                        acc[i][0] += r * cv0.x; acc[i][1] += r * cv0.y;
                        acc[i][2] += r * cv0.z; acc[i][3] += r * cv0.w;
                        acc[i][4] += r * cv1.x; acc[i][5] += r * cv1.y;
                        acc[i][6] += r * cv1.z; acc[i][7] += r * cv1.w;
                    }
                }
            }
        }
        // ---- argmin: per-wave reduce over 64 lanes, then cross-wave via global ----
        {
            float4 cn0 = *reinterpret_cast<const float4*>(cnorm + q * 1024 + kb);
            float4 cn1 = *reinterpret_cast<const float4*>(cnorm + q * 1024 + kb + 256);
            float c0e[4] = {cn0.x, cn0.y, cn0.z, cn0.w};
            float c1e[4] = {cn1.x, cn1.y, cn1.z, cn1.w};
#pragma unroll
            for (int i = 0; i < 8; ++i) {
                unsigned long long k = 0xFFFFFFFFFFFFFFFFull;
#pragma unroll
                for (int e = 0; e < 4; ++e) {
                    unsigned long long ka = distkey(c0e[e] - 2.f * acc[i][e], kb + e);
                    unsigned long long kc = distkey(c1e[e] - 2.f * acc[i][4 + e],
                                                    kb + 256 + e);
                    if (ka < k) k = ka;
                    if (kc < k) k = kc;
                }
                for (int off = 32; off >= 1; off >>= 1) {
                    unsigned long long o = __shfl_xor(k, off, 64);
                    if (o < k) k = o;
                }
                if (lane == 0) partg[blk * 32 + kg * 16 + bg * 8 + i] = k;
            }
        }
        __syncthreads();  // drains the global stores (vmcnt) before cross-read
        if (tid < 16) {
            unsigned long long ka = partg[blk * 32 + tid];
            unsigned long long kc = partg[blk * 32 + 16 + tid];
            if (kc < ka) ka = kc;
            const int idx = (int)(ka & 0xFFFFFFFFu);
            idxg[blk * 16 + tid] = idx;
            out[(b0 + tid) * 8 + q] = (float)idx;
        }
        __syncthreads();
        // residual update (coalesced; idx uniform per it)
        for (int it = 0; it < 16; ++it) {
            const int idx = idxg[blk * 16 + it];
            rs[it * 256 + tid] -= cb[((size_t)(q * 1024 + idx)) * 256 + tid];
        }
        // next stage's top barrier publishes these rs writes
    }
}

extern "C" void kernel_launch(void* const* d_in, const int* in_sizes, int n_in,
                              void* d_out, int out_size, void* d_ws, size_t ws_size,
                              hipStream_t stream) {
    const float* audio = (const float*)d_in[0];
    const float* state = (const float*)d_in[1];
    const float* W0 = (const float*)d_in[2];
    const float* b0 = (const float*)d_in[3];
    const float* W1 = (const float*)d_in[4];
    const float* b1 = (const float*)d_in[5];
    const float* W2 = (const float*)d_in[6];
    const float* b2 = (const float*)d_in[7];
    const float* W3 = (const float*)d_in[8];
    const float* b3 = (const float*)d_in[9];
    const float* cbk = (const float*)d_in[10];
    float* out = (float*)d_out;

    float* cnorm_ws = (float*)d_ws;            // 8192
    float* r_ws = cnorm_ws + 8192;             // 2097152
    float* W1T = r_ws + 2097152;               // 65536
    float* W2T = W1T + 65536;                  // 327680
    float* W3T = W2T + 327680;                 // 393216
    float* y1g = W3T + 393216;                 // 33554432
    float* cbT = y1g + 33554432;               // 2097152 (8MB staged codebook)
    float* extra = cbT + 2097152;              // argmin scratch (~164KB)
    // total ~154.3 MB; ws>=196MB proven in r7 (split path ran)

    volatile unsigned long long* partg = (volatile unsigned long long*)extra;
    volatile int* idxg = (volatile int*)(extra + 32768);

    cnorm_kernel<<<32, 256, 0, stream>>>(cbk, cnorm_ws);
    cbtrans_kernel<<<2048, 256, 0, stream>>>(cbk, cbT);
    wtrans_kernel<<<416, 256, 0, stream>>>(W1, W2, W3, W1T, W2T, W3T);
    convA_kernel<<<8192, 256, 0, stream>>>(audio, W0, b0, W1T, b1, y1g);
    convB_kernel<<<8192 / GB, 256, 0, stream>>>(state, b2, b3, W2T, W3T, y1g,
                                                out, r_ws);
    rvq_kernel<<<512, 256, 0, stream>>>(cbk, cbT, cnorm_ws, r_ws, out, partg, idxg);
}

// Round 10
// 1990.932 us; speedup vs baseline: 1.2476x; 1.1824x over previous
//
#include <hip/hip_runtime.h>
#include <hip/hip_bf16.h>

#define GB 2  // batch elems per convB block

__device__ __forceinline__ float elu1(float v) { return v > 0.f ? v : expm1f(v); }

// ---------------- cnorm: ||cb_k||^2 per code ----------------
__global__ void cnorm_kernel(const float* __restrict__ cb, float* __restrict__ cnorm) {
    int g = blockIdx.x * blockDim.x + threadIdx.x;  // 0..8191  (q*1024+k)
    if (g >= 8 * 1024) return;
    const float* p = cb + (size_t)g * 256;
    float s = 0.f;
    for (int d = 0; d < 256; d += 4) {
        float4 v = *reinterpret_cast<const float4*>(p + d);
        s += v.x * v.x + v.y * v.y + v.z * v.z + v.w * v.w;
    }
    cnorm[g] = s;
}

// ---------------- cbtrans: codebook -> stage-major layout -------------------
// cbT[(s*8 + dl)*1024 + k] = cb[((s>>5)*1024 + k)*256 + (s&31)*8 + dl]
__global__ void cbtrans_kernel(const float* __restrict__ cb, float* __restrict__ cbT) {
    int t = blockIdx.x * blockDim.x + threadIdx.x;  // 0..524287 (float4 units)
    int o = t * 4;
    const int s = o >> 13;          // stage 0..255
    const int r = o & 8191;
    const int dl = r >> 10;
    const int k = r & 1023;         // k..k+3
    const int q = s >> 5;
    const int d = (s & 31) * 8 + dl;
    const float* src = cb + ((size_t)(q * 1024 + k)) * 256 + d;
    float4 v;
    v.x = src[0 * 256]; v.y = src[1 * 256]; v.z = src[2 * 256]; v.w = src[3 * 256];
    *reinterpret_cast<float4*>(cbT + o) = v;
}

// ---------------- weight transpose to lane-major layouts ----------------
__global__ void wtrans_kernel(const float* __restrict__ W1, const float* __restrict__ W2,
                              const float* __restrict__ W3, float* __restrict__ W1T,
                              float* __restrict__ W2T, float* __restrict__ W3T) {
    int g = blockIdx.x * blockDim.x + threadIdx.x;
    if (g < 8192) {  // W1
        int ci = g >> 7, c = g & 127;
        const float* src = W1 + c * 512 + ci * 8;
        float4 a = *reinterpret_cast<const float4*>(src);
        float4 b = *reinterpret_cast<const float4*>(src + 4);
        *reinterpret_cast<float4*>(W1T + g * 8) = a;
        *reinterpret_cast<float4*>(W1T + g * 8 + 4) = b;
    }
    int g2 = g - 8192;
    if (g2 >= 0 && g2 < 32768) {  // W2
        int ci = g2 >> 8, c = g2 & 255;
        const float* src = W2 + c * 1280 + ci * 10;
        float* dst = W2T + g2 * 10;
#pragma unroll
        for (int j = 0; j < 5; ++j)
            *reinterpret_cast<float2*>(dst + 2 * j) =
                *reinterpret_cast<const float2*>(src + 2 * j);
    }
    int g3 = g - 40960;
    if (g3 >= 0 && g3 < 65536) {  // W3 (only taps 6..11 are ever used)
        int ci = g3 >> 8, c = g3 & 255;
        const float* src = W3 + c * 3072 + ci * 12 + 6;
        float* dst = W3T + g3 * 6;
#pragma unroll
        for (int j = 0; j < 3; ++j)
            *reinterpret_cast<float2*>(dst + 2 * j) =
                *reinterpret_cast<const float2*>(src + 2 * j);
    }
}

// ================= convA: conv0 + conv1 (r5 proven) ==========================
__global__ __launch_bounds__(256, 2)
void convA_kernel(const float* __restrict__ audio,
                  const float* __restrict__ W0, const float* __restrict__ b0,
                  const float* __restrict__ W1T, const float* __restrict__ b1,
                  float* __restrict__ y1g) {
    __shared__ __align__(16) float xs[244];
    __shared__ __align__(16) float y0s[64 * 124];  // 4 left pad cols

    const int tid = threadIdx.x;
    const int b = blockIdx.x;

    if (tid < 64) {
        y0s[tid * 124 + 0] = 0.f; y0s[tid * 124 + 1] = 0.f;
        y0s[tid * 124 + 2] = 0.f; y0s[tid * 124 + 3] = 0.f;
    }
    if (tid < 242) xs[tid] = (tid < 2) ? 0.f : audio[b * 240 + tid - 2];
    __syncthreads();
    {
        const int ci = tid >> 2, tg = tid & 3;
        float4 w = *reinterpret_cast<const float4*>(W0 + ci * 4);
        float bias = b0[ci];
        for (int t = tg; t < 120; t += 4) {
            float v = bias + w.x * xs[2 * t] + w.y * xs[2 * t + 1]
                           + w.z * xs[2 * t + 2] + w.w * xs[2 * t + 3];
            y0s[ci * 124 + 4 + t] = elu1(v);
        }
    }
    __syncthreads();
    {
        const int c = tid >> 1, half = tid & 1, t0 = 15 * half;
        float acc[15];
        float bias = b1[c];
#pragma unroll
        for (int u = 0; u < 15; ++u) acc[u] = bias;
        const float* wbase = W1T + c * 8;  // + ci*1024
        for (int ci = 0; ci < 64; ++ci) {
            float4 wA = *reinterpret_cast<const float4*>(wbase + ci * 1024);
            float4 wB = *reinterpret_cast<const float4*>(wbase + ci * 1024 + 4);
            const float* yb = y0s + ci * 124 + 4 * t0;
#pragma unroll
            for (int u = 0; u < 15; ++u) {
                float4 a = *reinterpret_cast<const float4*>(yb + 4 * u);
                float4 d = *reinterpret_cast<const float4*>(yb + 4 * u + 4);
                acc[u] += wA.x * a.x + wA.y * a.y + wA.z * a.z + wA.w * a.w
                        + wB.x * d.x + wB.y * d.y + wB.z * d.z + wB.w * d.w;
            }
        }
        float* yo = y1g + ((size_t)b * 128 + c) * 32 + t0;
#pragma unroll
        for (int u = 0; u < 15; ++u) yo[u] = elu1(acc[u]);
    }
}

// ================= convB fused (r5 proven) ===================================
__global__ __launch_bounds__(256, 2)
void convB_kernel(const float* __restrict__ state_in,
                  const float* __restrict__ b2, const float* __restrict__ b3,
                  const float* __restrict__ W2T, const float* __restrict__ W3T,
                  const float* __restrict__ y1g,
                  float* __restrict__ out, float* __restrict__ r_ws) {
    __shared__ __align__(16) float y1s[GB * 128 * 32];
    __shared__ __align__(16) float y2s[GB * 256 * 6];

    const int tid = threadIdx.x;
    const int bbase = blockIdx.x * GB;

    {
        const int col = tid & 31, grp = tid >> 5;
#pragma unroll
        for (int bi = 0; bi < GB; ++bi) {
            const float* src = y1g + ((size_t)(bbase + bi) * 128 + grp * 16) * 32 + col;
            float* dst = y1s + (bi * 128 + grp * 16) * 32 + col;
#pragma unroll
            for (int i = 0; i < 16; ++i) dst[i * 32] = src[i * 32];
        }
    }
    __syncthreads();
    {
        const int c = tid;
        float acc[GB][6];
        float bias = b2[c];
#pragma unroll
        for (int bi = 0; bi < GB; ++bi)
#pragma unroll
            for (int t = 0; t < 6; ++t) acc[bi][t] = bias;
        const float* wbase = W2T + c * 10;
        for (int ci = 0; ci < 128; ++ci) {
            float w[10];
#pragma unroll
            for (int jj = 0; jj < 5; ++jj) {
                float2 wv = *reinterpret_cast<const float2*>(wbase + ci * 2560 + jj * 2);
                w[jj * 2] = wv.x; w[jj * 2 + 1] = wv.y;
            }
#pragma unroll
            for (int bi = 0; bi < GB; ++bi) {
                const float* yr = y1s + (bi * 128 + ci) * 32;
                float row[32];
#pragma unroll
                for (int k4 = 0; k4 < 8; ++k4) {
                    float4 v = *reinterpret_cast<const float4*>(yr + k4 * 4);
                    row[k4 * 4] = v.x; row[k4 * 4 + 1] = v.y;
                    row[k4 * 4 + 2] = v.z; row[k4 * 4 + 3] = v.w;
                }
                acc[bi][0] += w[5] * row[0] + w[6] * row[1] + w[7] * row[2]
                            + w[8] * row[3] + w[9] * row[4];
#pragma unroll
                for (int t = 1; t < 6; ++t) {
                    const int q0 = 5 * t - 5;
                    float s = 0.f;
#pragma unroll
                    for (int j = 0; j < 10; ++j) s += w[j] * row[q0 + j];
                    acc[bi][t] += s;
                }
            }
        }
#pragma unroll
        for (int bi = 0; bi < GB; ++bi)
#pragma unroll
            for (int t = 0; t < 6; ++t)
                y2s[(bi * 256 + c) * 6 + t] = elu1(acc[bi][t]);
    }
    __syncthreads();
    {
        const int c = tid;
        float acc[GB];
        float bias = b3[c];
#pragma unroll
        for (int bi = 0; bi < GB; ++bi) acc[bi] = bias;
        const float* wbase = W3T + c * 6;
        for (int ci = 0; ci < 256; ++ci) {
            float2 w01 = *reinterpret_cast<const float2*>(wbase + ci * 1536);
            float2 w23 = *reinterpret_cast<const float2*>(wbase + ci * 1536 + 2);
            float2 w45 = *reinterpret_cast<const float2*>(wbase + ci * 1536 + 4);
#pragma unroll
            for (int bi = 0; bi < GB; ++bi) {
                const float* yr = y2s + (bi * 256 + ci) * 6;
                float2 a = *reinterpret_cast<const float2*>(yr);
                float2 d = *reinterpret_cast<const float2*>(yr + 2);
                float2 e = *reinterpret_cast<const float2*>(yr + 4);
                acc[bi] += w01.x * a.x + w01.y * a.y + w23.x * d.x + w23.y * d.y
                         + w45.x * e.x + w45.y * e.y;
            }
        }
#pragma unroll
        for (int bi = 0; bi < GB; ++bi) {
            const int b = bbase + bi;
            float y3 = acc[bi];
            r_ws[b * 256 + c] = y3;
            float4 si = *reinterpret_cast<const float4*>(state_in + b * 1024 + c * 4);
            float4 o; o.x = si.y; o.y = si.z; o.z = si.w; o.w = y3;
            *reinterpret_cast<float4*>(out + 65536 + b * 1024 + c * 4) = o;
        }
    }
}

// ---------------- RVQ v6: register-direct codebook, no staging ---------------
// 256 thr = 4 waves (2 bg x 2 kg), 16 b/block, grid 512.
// Codebook read straight from cbT (L2/L3-resident: all blocks stream the same
// 1MB/level slice in lockstep) into per-dp register arrays; LDS holds only the
// 16KB residual tile. ZERO barriers in the 256-stage hot loop (3 per q-level).
__device__ __forceinline__ unsigned long long distkey(float d, int k) {
    unsigned u = __float_as_uint(d);
    u = (u & 0x80000000u) ? ~u : (u | 0x80000000u);  // monotonic float->uint
    return ((unsigned long long)u << 32) | (unsigned)k;  // low idx wins ties (np argmin)
}

__global__ __launch_bounds__(256)
void rvq_kernel(const float* __restrict__ cb, const float* __restrict__ cbT,
                const float* __restrict__ cnorm, const float* __restrict__ r_ws,
                float* __restrict__ out) {
    __shared__ __align__(16) float rs[16 * 256];  // 16 KB residuals
    __shared__ unsigned long long part_sh[2][16];
    __shared__ int idx_sh[16];

    const int tid = threadIdx.x;
    const int lane = tid & 63;
    const int wid = tid >> 6;   // 0..3
    const int bg = wid >> 1;    // 0..1: b block of 8
    const int kg = wid & 1;     // 0..1: k half of 512
    const int b0 = blockIdx.x * 16;
    const int kb = kg * 512 + 4 * lane;  // cv0 k-base (cv1 = +256)

    // load residuals: 4096 floats
    for (int it = 0; it < 4; ++it) {
        int o = (it * 256 + tid) * 4;
        *reinterpret_cast<float4*>(rs + o) =
            *reinterpret_cast<const float4*>(r_ws + b0 * 256 + o);
    }
    __syncthreads();

    for (int q = 0; q < 8; ++q) {
        float acc[8][8];
#pragma unroll
        for (int i = 0; i < 8; ++i)
#pragma unroll
            for (int j = 0; j < 8; ++j) acc[i][j] = 0.f;

        for (int ds = 0; ds < 32; ++ds) {
            const float* sb = cbT + (size_t)(q * 32 + ds) * 8192;
#pragma unroll
            for (int dp = 0; dp < 2; ++dp) {
                // issue the 8 codebook vector loads for this d-quad up front
                float4 cv0[4], cv1[4];
#pragma unroll
                for (int dd = 0; dd < 4; ++dd) {
                    const int dl = dp * 4 + dd;
                    cv0[dd] = *reinterpret_cast<const float4*>(sb + dl * 1024 + kb);
                    cv1[dd] = *reinterpret_cast<const float4*>(sb + dl * 1024 + kb + 256);
                }
                float rr[8][4];
#pragma unroll
                for (int i = 0; i < 8; ++i) {
                    float4 t = *reinterpret_cast<const float4*>(
                        rs + (bg * 8 + i) * 256 + ds * 8 + dp * 4);
                    rr[i][0] = t.x; rr[i][1] = t.y; rr[i][2] = t.z; rr[i][3] = t.w;
                }
#pragma unroll
                for (int dd = 0; dd < 4; ++dd) {
#pragma unroll
                    for (int i = 0; i < 8; ++i) {
                        const float r = rr[i][dd];
                        acc[i][0] += r * cv0[dd].x; acc[i][1] += r * cv0[dd].y;
                        acc[i][2] += r * cv0[dd].z; acc[i][3] += r * cv0[dd].w;
                        acc[i][4] += r * cv1[dd].x; acc[i][5] += r * cv1[dd].y;
                        acc[i][6] += r * cv1[dd].z; acc[i][7] += r * cv1[dd].w;
                    }
                }
            }
        }
        // ---- argmin: wave reduce, then cross-wave via LDS ----
        {
            float4 cn0 = *reinterpret_cast<const float4*>(cnorm + q * 1024 + kb);
            float4 cn1 = *reinterpret_cast<const float4*>(cnorm + q * 1024 + kb + 256);
            float c0e[4] = {cn0.x, cn0.y, cn0.z, cn0.w};
            float c1e[4] = {cn1.x, cn1.y, cn1.z, cn1.w};
#pragma unroll
            for (int i = 0; i < 8; ++i) {
                unsigned long long k = 0xFFFFFFFFFFFFFFFFull;
#pragma unroll
                for (int e = 0; e < 4; ++e) {
                    unsigned long long ka = distkey(c0e[e] - 2.f * acc[i][e], kb + e);
                    unsigned long long kc = distkey(c1e[e] - 2.f * acc[i][4 + e],
                                                    kb + 256 + e);
                    if (ka < k) k = ka;
                    if (kc < k) k = kc;
                }
                for (int off = 32; off >= 1; off >>= 1) {
                    unsigned long long o = __shfl_xor(k, off, 64);
                    if (o < k) k = o;
                }
                if (lane == 0) part_sh[kg][bg * 8 + i] = k;
            }
        }
        __syncthreads();
        if (tid < 16) {
            unsigned long long ka = part_sh[0][tid];
            unsigned long long kc = part_sh[1][tid];
            if (kc < ka) ka = kc;
            const int idx = (int)(ka & 0xFFFFFFFFu);
            idx_sh[tid] = idx;
            out[(b0 + tid) * 8 + q] = (float)idx;
        }
        __syncthreads();
        // residual update (coalesced; idx uniform per it)
        for (int it = 0; it < 16; ++it) {
            const int idx = idx_sh[it];
            rs[it * 256 + tid] -= cb[((size_t)(q * 1024 + idx)) * 256 + tid];
        }
        __syncthreads();  // publish rs before next level's reads
    }
}

extern "C" void kernel_launch(void* const* d_in, const int* in_sizes, int n_in,
                              void* d_out, int out_size, void* d_ws, size_t ws_size,
                              hipStream_t stream) {
    const float* audio = (const float*)d_in[0];
    const float* state = (const float*)d_in[1];
    const float* W0 = (const float*)d_in[2];
    const float* b0 = (const float*)d_in[3];
    const float* W1 = (const float*)d_in[4];
    const float* b1 = (const float*)d_in[5];
    const float* W2 = (const float*)d_in[6];
    const float* b2 = (const float*)d_in[7];
    const float* W3 = (const float*)d_in[8];
    const float* b3 = (const float*)d_in[9];
    const float* cbk = (const float*)d_in[10];
    float* out = (float*)d_out;

    float* cnorm_ws = (float*)d_ws;            // 8192
    float* r_ws = cnorm_ws + 8192;             // 2097152
    float* W1T = r_ws + 2097152;               // 65536
    float* W2T = W1T + 65536;                  // 327680
    float* W3T = W2T + 327680;                 // 393216
    float* y1g = W3T + 393216;                 // 33554432
    float* cbT = y1g + 33554432;               // 2097152 (8MB staged codebook)
    // total ~154 MB; ws>=196MB proven in r7

    cnorm_kernel<<<32, 256, 0, stream>>>(cbk, cnorm_ws);
    cbtrans_kernel<<<2048, 256, 0, stream>>>(cbk, cbT);
    wtrans_kernel<<<416, 256, 0, stream>>>(W1, W2, W3, W1T, W2T, W3T);
    convA_kernel<<<8192, 256, 0, stream>>>(audio, W0, b0, W1T, b1, y1g);
    convB_kernel<<<8192 / GB, 256, 0, stream>>>(state, b2, b3, W2T, W3T, y1g,
                                                out, r_ws);
    rvq_kernel<<<512, 256, 0, stream>>>(cbk, cbT, cnorm_ws, r_ws, out);
}